// Round 5
// baseline (1170.724 us; speedup 1.0000x reference)
//
#include <hip/hip_runtime.h>
#include <math.h>

// Problem constants
#define NSEQ 4
#define BATCH 256
#define T 64
#define FIN 32
#define S 512
#define KTOT 544     // FIN + S unified k-dimension

// Pipelined decomposition: 4 lanes concurrent (lane i lags i-1 by 1 step).
// Per lane: 16 groups x 16 rows, 8 slice-WGs x 64 cols. 4*16*8 = 512 WGs.
// NT=512 (8 waves); 2 WGs/CU (LDS 73KB<=80KB, VGPR capped 128) -> 4 waves/SIMD.
#define NT 512
#define NWG 512
#define RPG 16
#define SW 64
#define DEPTH 4
#define KPW 68       // k per wave (544/8)

// ws float offsets
#define RING_SZ  (4ull * DEPTH * BATCH * S)        // 8 MB state ring
#define OUTP_OFF RING_SZ                            // [gid][sl][16] partials
#define CTL_OFF  (RING_SZ + 16384ull)               // counters: gid*32 uints

#define FLAG_MAGIC 0x13572468u

#define HS2 548   // h_lds row stride: [x(32)|hc(512)] + pad4 (16B-aligned rows)
#define RS2 66    // red row stride (64+2)

__device__ __forceinline__ unsigned ld_cnt(const unsigned* p) {
  return __hip_atomic_load(p, __ATOMIC_RELAXED, __HIP_MEMORY_SCOPE_AGENT);
}

// ---- coherent (MALL) ring I/O via sc0 sc1 asm (R4-proven) -----------------
__device__ __forceinline__ void cstore1(float* p, float v) {
  asm volatile("global_store_dword %0, %1, off sc0 sc1" :: "v"(p), "v"(v) : "memory");
}
__device__ __forceinline__ float cload1(const float* p) {
  float v;
  asm volatile("global_load_dword %0, %1, off sc0 sc1\n\ts_waitcnt vmcnt(0)"
               : "=v"(v) : "v"(p) : "memory");
  return v;
}
__device__ __forceinline__ void cload_row(float4* d, const float* p) {
  asm volatile(
      "global_load_dwordx4 %0, %4, off sc0 sc1\n\t"
      "global_load_dwordx4 %1, %4, off offset:512 sc0 sc1\n\t"
      "global_load_dwordx4 %2, %4, off offset:1024 sc0 sc1\n\t"
      "global_load_dwordx4 %3, %4, off offset:1536 sc0 sc1\n\t"
      "s_waitcnt vmcnt(0)"
      : "=&v"(d[0]), "=&v"(d[1]), "=&v"(d[2]), "=&v"(d[3])
      : "v"(p) : "memory");
}
__device__ __forceinline__ void cload_row2(float4* h, float4* q,
                                           const float* ph, const float* pp) {
  asm volatile(
      "global_load_dwordx4 %0, %8, off sc0 sc1\n\t"
      "global_load_dwordx4 %1, %8, off offset:512 sc0 sc1\n\t"
      "global_load_dwordx4 %2, %8, off offset:1024 sc0 sc1\n\t"
      "global_load_dwordx4 %3, %8, off offset:1536 sc0 sc1\n\t"
      "global_load_dwordx4 %4, %9, off sc0 sc1\n\t"
      "global_load_dwordx4 %5, %9, off offset:512 sc0 sc1\n\t"
      "global_load_dwordx4 %6, %9, off offset:1024 sc0 sc1\n\t"
      "global_load_dwordx4 %7, %9, off offset:1536 sc0 sc1\n\t"
      "s_waitcnt vmcnt(0)"
      : "=&v"(h[0]), "=&v"(h[1]), "=&v"(h[2]), "=&v"(h[3]),
        "=&v"(q[0]), "=&v"(q[1]), "=&v"(q[2]), "=&v"(q[3])
      : "v"(ph), "v"(pp) : "memory");
}

extern "C" __global__ void __launch_bounds__(NT, 4)
rnn_pipe2(const float* __restrict__ x,      // [4][256][64][32]
          const float* __restrict__ Wcell,  // [4][544][512]
          const float* __restrict__ bcell,  // [4][512]
          const float* __restrict__ Wcomb,  // [3][1024]
          const float* __restrict__ bcomb,  // [3]
          const float* __restrict__ Wout,   // [512]
          float* __restrict__ out,          // [1024] = [lane][batch]
          float* __restrict__ ws)
{
  const int b    = blockIdx.x;
  const int sl   = b & 7;          // slice (round-robins XCDs)
  const int gid  = b >> 3;         // 0..63 = lane*16 + grp
  const int lane = gid >> 4;
  const int grp  = gid & 15;
  const int r0 = grp * RPG, sb = sl * SW;
  const int tid = threadIdx.x;

  __shared__ __align__(16) float h_lds[RPG * HS2];  // 35.1 KB [x|hc] rows
  __shared__ __align__(16) float red[8 * RPG * RS2]; // 33.8 KB [kc][r][col]
  __shared__ float wg_lds[2 * S];                    //  4.0 KB gate weights
  __shared__ float obuf[16];

  float* ring = ws;
  unsigned* ctl      = (unsigned*)(ws + CTL_OFF);
  unsigned* cnt_own  = ctl + gid * 32;
  unsigned* flg_own  = cnt_own + 16;
  unsigned* cnt_prod = ctl + (gid - 16) * 32;  // valid iff lane>0
  unsigned* cnt_cons = ctl + (gid + 16) * 32;  // valid iff lane<3

  // ---- init handshake (poison-keyed flag; kernel-end writeback of the
  //      harness memset means no dirty poison lines remain -> no fences) ----
  if (sl == 0 && tid == 0) {
    __hip_atomic_store(cnt_own, 0u, __ATOMIC_RELAXED, __HIP_MEMORY_SCOPE_AGENT);
    __hip_atomic_store(flg_own, FLAG_MAGIC, __ATOMIC_RELEASE, __HIP_MEMORY_SCOPE_AGENT);
  }
  if (tid == 0) {
    while (__hip_atomic_load(flg_own, __ATOMIC_ACQUIRE, __HIP_MEMORY_SCOPE_AGENT) != FLAG_MAGIC)
      __builtin_amdgcn_s_sleep(1);
    if (lane > 0)
      while (__hip_atomic_load(cnt_prod + 16, __ATOMIC_ACQUIRE, __HIP_MEMORY_SCOPE_AGENT) != FLAG_MAGIC)
        __builtin_amdgcn_s_sleep(1);
    if (lane < 3)
      while (__hip_atomic_load(cnt_cons + 16, __ATOMIC_ACQUIRE, __HIP_MEMORY_SCOPE_AGENT) != FLAG_MAGIC)
        __builtin_amdgcn_s_sleep(1);
  }

  // ---- per-thread constants ----
  const float* Wc = Wcell + (size_t)lane * KTOT * S;
  const int kc  = tid >> 6;        // wave = k-chunk [kc*68, kc*68+68)
  const int col = tid & 63;        // this thread's s-column within slice
  float U2[KPW];                   // 68 VGPRs, resident all steps
  #pragma unroll
  for (int k = 0; k < KPW; ++k)
    U2[k] = Wc[(size_t)(kc * KPW + k) * S + sb + col];
  const float bcv = bcell[lane * S + sb + col];
  const float wov = Wout[sb + col];
  for (int idx = tid; idx < 2 * S; idx += NT)
    wg_lds[idx] = (lane > 0) ? Wcomb[(size_t)(lane - 1) * 2 * S + idx] : 0.0f;
  const float bg = (lane > 0) ? bcomb[lane - 1] : 0.0f;
  // stage/gate mapping: 32 threads per row
  const int grow = tid >> 5, gch = tid & 31;
  // reduce mapping: rows {rb, rb+8}
  const int rb = tid >> 6;
  __syncthreads();

  float oacc0 = 0.f, oacc1 = 0.f;

  for (int t = 0; t < T; ++t) {
    // ---- phase A: x stage (h_lds x-region free after prev syncD) + polls --
    h_lds[grow * HS2 + gch] =
        x[(((size_t)lane * BATCH + r0 + grow) * T + t) * FIN + gch];
    if (tid == 0) {
      if (t > 0)                  while (ld_cnt(cnt_own)  < 8u * (unsigned)t) {}
      if (lane > 0)               while (ld_cnt(cnt_prod) < 8u * (unsigned)(t + 1)) {}
      if (lane < 3 && t >= DEPTH) while (ld_cnt(cnt_cons) < 8u * (unsigned)(t - 3)) {}
    }
    __syncthreads();

    // ---- phase B: coherent ring loads + wave-local gate + stage hc --------
    float4 hv[4], pv[4];
    const float* hb = ring + ((size_t)(lane * DEPTH + ((t - 1) & 3)) * BATCH + r0 + grow) * S + gch * 4;
    const float* pb = ring + ((size_t)((lane - 1) * DEPTH + (t & 3)) * BATCH + r0 + grow) * S + gch * 4;
    if (t > 0) {
      if (lane > 0) cload_row2(hv, pv, hb, pb);
      else          cload_row(hv, hb);
    } else {
      #pragma unroll
      for (int j = 0; j < 4; ++j) hv[j] = make_float4(0.f, 0.f, 0.f, 0.f);
      if (lane > 0) cload_row(pv, pb);
    }
    if (lane > 0) {
      float gs = 0.0f;
      #pragma unroll
      for (int j = 0; j < 4; ++j) {
        const float* wh = &wg_lds[j * 128 + gch * 4];
        const float* wp = wh + S;
        gs += hv[j].x * wh[0] + hv[j].y * wh[1] + hv[j].z * wh[2] + hv[j].w * wh[3];
        gs += pv[j].x * wp[0] + pv[j].y * wp[1] + pv[j].z * wp[2] + pv[j].w * wp[3];
      }
      gs += __shfl_xor(gs, 1);  gs += __shfl_xor(gs, 2);  gs += __shfl_xor(gs, 4);
      gs += __shfl_xor(gs, 8);  gs += __shfl_xor(gs, 16);  // 32-lane row halves
      const float w = 1.0f / (1.0f + __expf(-(gs + bg)));
      #pragma unroll
      for (int j = 0; j < 4; ++j) {  // hc = p + w*(h-p)
        hv[j].x = fmaf(w, hv[j].x - pv[j].x, pv[j].x);
        hv[j].y = fmaf(w, hv[j].y - pv[j].y, pv[j].y);
        hv[j].z = fmaf(w, hv[j].z - pv[j].z, pv[j].z);
        hv[j].w = fmaf(w, hv[j].w - pv[j].w, pv[j].w);
      }
    }
    #pragma unroll
    for (int j = 0; j < 4; ++j)
      *(float4*)&h_lds[grow * HS2 + 32 + j * 128 + gch * 4] = hv[j];
    __syncthreads();

    // ---- phase C: matvec over unified [x|hc] rows, all 16 rows, 1 pass ----
    #pragma unroll
    for (int r = 0; r < RPG; ++r) {
      const float* hrow = &h_lds[r * HS2 + kc * KPW];  // 272B-aligned (17x16B)
      float a0 = 0.f, a1 = 0.f;
      #pragma unroll
      for (int u = 0; u < 17; ++u) {
        const float4 h4 = *(const float4*)(hrow + u * 4);  // wave-uniform bcast
        a0 = fmaf(h4.x, U2[u * 4 + 0], a0);
        a1 = fmaf(h4.y, U2[u * 4 + 1], a1);
        a0 = fmaf(h4.z, U2[u * 4 + 2], a0);
        a1 = fmaf(h4.w, U2[u * 4 + 3], a1);
      }
      red[(kc * RPG + r) * RS2 + col] = a0 + a1;
    }
    __syncthreads();

    // ---- phase D: reduce 8 kc + tanh + coherent store ---------------------
    float* slot = ring + ((size_t)(lane * DEPTH + (t & 3)) * BATCH + r0) * S + sb;
    #pragma unroll
    for (int j = 0; j < 2; ++j) {
      const int r = rb + 8 * j;
      float s2 = bcv;
      #pragma unroll
      for (int c = 0; c < 8; ++c) s2 += red[(c * RPG + r) * RS2 + col];
      const float aa = fabsf(s2), ee = __expf(2.0f * aa);
      const float th = copysignf(1.0f - 2.0f / (ee + 1.0f), s2);
      cstore1(slot + (size_t)r * S + col, th);
      if (t == T - 1) { if (j == 0) oacc0 = th * wov; else oacc1 = th * wov; }
    }
    __syncthreads();  // drains vmcnt -> cstores at MALL before arrive
    if (tid == 0)
      __hip_atomic_fetch_add(cnt_own, 1u, __ATOMIC_RELAXED, __HIP_MEMORY_SCOPE_AGENT);
  }

  // ---- output: out[lane*256 + r] = h_T[r] . Wout --------------------------
  {
    float v0 = oacc0, v1 = oacc1;
    #pragma unroll
    for (int m = 1; m < 64; m <<= 1) { v0 += __shfl_xor(v0, m); v1 += __shfl_xor(v1, m); }
    if ((tid & 63) == 0) { obuf[rb] = v0; obuf[rb + 8] = v1; }  // rows {rb, rb+8}
  }
  __syncthreads();
  if (tid < 16)
    cstore1(ws + OUTP_OFF + (size_t)((gid * 8 + sl) * 16 + tid), obuf[tid]);
  __syncthreads();
  if (tid == 0)
    __hip_atomic_fetch_add(cnt_own, 1u, __ATOMIC_RELAXED, __HIP_MEMORY_SCOPE_AGENT);
  if (sl == 0) {
    if (tid == 0)
      while (ld_cnt(cnt_own) < 8u * (unsigned)(T + 1)) {}
    __syncthreads();
    if (tid < 128) {
      const int sli = tid >> 4, r = tid & 15;
      red[tid] = cload1(ws + OUTP_OFF + (size_t)((gid * 8 + sli) * 16 + r));
    }
    __syncthreads();
    if (tid < 16) {
      float s2 = 0.f;
      #pragma unroll
      for (int sli = 0; sli < 8; ++sli) s2 += red[sli * 16 + tid];
      out[lane * BATCH + r0 + tid] = s2;
    }
  }
}

extern "C" void kernel_launch(void* const* d_in, const int* in_sizes, int n_in,
                              void* d_out, int out_size, void* d_ws, size_t ws_size,
                              hipStream_t stream) {
  (void)in_sizes; (void)n_in; (void)out_size; (void)ws_size;
  rnn_pipe2<<<dim3(NWG), dim3(NT), 0, stream>>>(
      (const float*)d_in[0],   // inputs
      (const float*)d_in[1],   // W_cell
      (const float*)d_in[2],   // b_cell
      (const float*)d_in[3],   // W_comb
      (const float*)d_in[4],   // b_comb
      (const float*)d_in[5],   // W_out
      (float*)d_out,
      (float*)d_ws);
}